// Round 1
// baseline (283.215 us; speedup 1.0000x reference)
//
#include <hip/hip_runtime.h>
#include <hip/hip_bf16.h>

typedef __attribute__((ext_vector_type(8))) short short8;
typedef __attribute__((ext_vector_type(4))) float float4v;

#define LOG2E 1.44269504088896340736f

__device__ __forceinline__ unsigned short f2bf(float f) {
    unsigned int u = __float_as_uint(f);
    unsigned int r = (u + 0x7fffu + ((u >> 16) & 1u)) >> 16;  // RNE
    return (unsigned short)r;
}

// ---------------------------------------------------------------------------
// Kernel 1: convert Wk|Wq|Wv (fp32) -> combined bf16 weight matrix Wb[192][1024]
// rows 0-63 = Wk, 64-127 = Wq, 128-191 = Wv
// ---------------------------------------------------------------------------
__global__ void wconv_kernel(const float* __restrict__ Wk, const float* __restrict__ Wq,
                             const float* __restrict__ Wv, unsigned short* __restrict__ Wb) {
    int i = blockIdx.x * 256 + threadIdx.x;  // 0..196607
    if (i >= 192 * 1024) return;
    float v;
    if (i < 65536)       v = Wk[i];
    else if (i < 131072) v = Wq[i - 65536];
    else                 v = Wv[i - 131072];
    Wb[i] = f2bf(v);
}

// ---------------------------------------------------------------------------
// Kernel 2: projection GEMM. C[16384,192] = X[16384,1024] @ Wb^T
// block = 256 threads (4 waves), each wave: 16 rows x 192 cols.
// Outputs: ks[b][t][64], qs[b][t][64] (pre-scaled by 1/8), vT[b][o][t] (transposed)
// ---------------------------------------------------------------------------
__global__ __launch_bounds__(256) void proj_kernel(
    const float* __restrict__ x, const unsigned short* __restrict__ Wb,
    unsigned short* __restrict__ qs, unsigned short* __restrict__ ks,
    unsigned short* __restrict__ vT) {
    const int lane = threadIdx.x & 63;
    const int wave = threadIdx.x >> 6;
    const int quad = lane >> 4;
    const int l16  = lane & 15;
    const int rowA = blockIdx.x * 64 + wave * 16 + l16;  // A-operand row (m = lane&15)

    float4v acc[12];
#pragma unroll
    for (int n = 0; n < 12; n++) acc[n] = (float4v){0.f, 0.f, 0.f, 0.f};

    const float* xp = x + (size_t)rowA * 1024 + quad * 8;

    for (int kc = 0; kc < 32; kc++) {
        // A fragment: X[rowA][kc*32 + quad*8 .. +7] -> bf16
        float4v a0 = *(const float4v*)(xp + kc * 32);
        float4v a1 = *(const float4v*)(xp + kc * 32 + 4);
        short8 af;
#pragma unroll
        for (int j = 0; j < 4; j++) af[j] = (short)f2bf(a0[j]);
#pragma unroll
        for (int j = 0; j < 4; j++) af[4 + j] = (short)f2bf(a1[j]);
        // B fragments: Wb[h = n*16+l16][kc*32 + quad*8 .. +7]  (contiguous 16 B)
#pragma unroll
        for (int n = 0; n < 12; n++) {
            const short8 bf = *(const short8*)(Wb + (size_t)(n * 16 + l16) * 1024 + kc * 32 + quad * 8);
            acc[n] = __builtin_amdgcn_mfma_f32_16x16x32_bf16(af, bf, acc[n], 0, 0, 0);
        }
    }

    // Epilogue. C layout: row = quad*4 + r, col = l16.
    const int rowD = blockIdx.x * 64 + wave * 16 + quad * 4;
#pragma unroll
    for (int r = 0; r < 4; r++) {
        const int t = rowD + r;
        const int b = t >> 11, tt = t & 2047;
#pragma unroll
        for (int n = 0; n < 4; n++)  // k heads
            ks[(size_t)t * 64 + n * 16 + l16] = f2bf(acc[n][r]);
#pragma unroll
        for (int n = 0; n < 4; n++)  // q heads, fold in HS^-0.5 = 1/8 (exact in bf16)
            qs[(size_t)t * 64 + n * 16 + l16] = f2bf(acc[4 + n][r] * 0.125f);
#pragma unroll
        for (int n = 0; n < 4; n++)  // v heads, transposed store vT[b][o][t]
            vT[(size_t)b * 131072 + (size_t)(n * 16 + l16) * 2048 + tt] = f2bf(acc[8 + n][r]);
    }
}

// ---------------------------------------------------------------------------
// Kernel 3: causal flash attention. 1 wave per block, 16 Q-rows per block.
// grid = (128 row-tiles, 8 batches). Online softmax, key blocks of 64.
// ---------------------------------------------------------------------------
__global__ __launch_bounds__(64) void attn_kernel(
    const unsigned short* __restrict__ qs, const unsigned short* __restrict__ ks,
    const unsigned short* __restrict__ vT, float* __restrict__ out) {
    // P transpose buffer: 16 rows x 64 keys, stride 72 (pad +8 -> 2-way bank alias, free)
    __shared__ unsigned short P[16 * 72];

    const int lane = threadIdx.x;
    const int quad = lane >> 4;
    const int l16  = lane & 15;
    const int rt = blockIdx.x;   // 0..127
    const int b  = blockIdx.y;   // 0..7
    const int t0 = rt * 16;

    const unsigned short* qb = qs + (size_t)b * 131072;
    const unsigned short* kb = ks + (size_t)b * 131072;
    const unsigned short* vb = vT + (size_t)b * 131072;

    // Q fragments (A-operand): Q[t0+l16][kc*32 + quad*8 .. +7]
    const short8 qf0 = *(const short8*)(qb + (size_t)(t0 + l16) * 64 + quad * 8);
    const short8 qf1 = *(const short8*)(qb + (size_t)(t0 + l16) * 64 + 32 + quad * 8);

    float4v o[4];
#pragma unroll
    for (int ot = 0; ot < 4; ot++) o[ot] = (float4v){0.f, 0.f, 0.f, 0.f};
    float mrow[4] = {-1e30f, -1e30f, -1e30f, -1e30f};
    float lrow[4] = {0.f, 0.f, 0.f, 0.f};

    const int nkb = t0 / 64 + 1;  // key blocks needed (causal)
    for (int j = 0; j < nkb; j++) {
        const int key0 = j * 64;
        // ---- S = Q K^T over 64 keys (4 tiles of 16), HS=64 (2 MFMA steps) ----
        float4v s[4];
#pragma unroll
        for (int kt = 0; kt < 4; kt++) {
            const unsigned short* kr = kb + (size_t)(key0 + kt * 16 + l16) * 64 + quad * 8;
            const short8 kf0 = *(const short8*)(kr);
            const short8 kf1 = *(const short8*)(kr + 32);
            float4v z = (float4v){0.f, 0.f, 0.f, 0.f};
            z = __builtin_amdgcn_mfma_f32_16x16x32_bf16(qf0, kf0, z, 0, 0, 0);
            s[kt] = __builtin_amdgcn_mfma_f32_16x16x32_bf16(qf1, kf1, z, 0, 0, 0);
        }
        // ---- causal mask: only the diagonal (last) block needs it ----
        if (j == nkb - 1) {
#pragma unroll
            for (int kt = 0; kt < 4; kt++) {
                const int key = key0 + kt * 16 + l16;
#pragma unroll
                for (int r = 0; r < 4; r++) {
                    if (key > t0 + quad * 4 + r) s[kt][r] = -1e30f;
                }
            }
        }
        // ---- online softmax (rows = quad*4 + r, replicated across 16 lanes) ----
        float mnew[4], alpha[4];
#pragma unroll
        for (int r = 0; r < 4; r++) {
            float mx = fmaxf(fmaxf(s[0][r], s[1][r]), fmaxf(s[2][r], s[3][r]));
            mx = fmaxf(mx, __shfl_xor(mx, 1));
            mx = fmaxf(mx, __shfl_xor(mx, 2));
            mx = fmaxf(mx, __shfl_xor(mx, 4));
            mx = fmaxf(mx, __shfl_xor(mx, 8));
            mnew[r]  = fmaxf(mrow[r], mx);
            alpha[r] = exp2f((mrow[r] - mnew[r]) * LOG2E);
            mrow[r]  = mnew[r];
        }
#pragma unroll
        for (int r = 0; r < 4; r++) {
            float rs = 0.f;
#pragma unroll
            for (int kt = 0; kt < 4; kt++) {
                float p = exp2f((s[kt][r] - mnew[r]) * LOG2E);
                rs += p;
                P[(quad * 4 + r) * 72 + kt * 16 + l16] = f2bf(p);
            }
            rs += __shfl_xor(rs, 1);
            rs += __shfl_xor(rs, 2);
            rs += __shfl_xor(rs, 4);
            rs += __shfl_xor(rs, 8);
            lrow[r] = lrow[r] * alpha[r] + rs;
#pragma unroll
            for (int ot = 0; ot < 4; ot++) o[ot][r] *= alpha[r];
        }
        // ---- O += P @ V  (P via LDS C->A transpose; V from transposed vT) ----
#pragma unroll
        for (int kc = 0; kc < 2; kc++) {
            const short8 pf = *(const short8*)(&P[l16 * 72 + kc * 32 + quad * 8]);
#pragma unroll
            for (int ot = 0; ot < 4; ot++) {
                const short8 vf = *(const short8*)(vb + (size_t)(ot * 16 + l16) * 2048 + key0 + kc * 32 + quad * 8);
                o[ot] = __builtin_amdgcn_mfma_f32_16x16x32_bf16(pf, vf, o[ot], 0, 0, 0);
            }
        }
    }

    // ---- epilogue: out[b][t][o] = O / l ----
    float* ob = out + (size_t)b * 2048 * 64;
#pragma unroll
    for (int r = 0; r < 4; r++) {
        const float inv = 1.0f / lrow[r];
        const int t = t0 + quad * 4 + r;
#pragma unroll
        for (int ot = 0; ot < 4; ot++) ob[(size_t)t * 64 + ot * 16 + l16] = o[ot][r] * inv;
    }
}

// ---------------------------------------------------------------------------
extern "C" void kernel_launch(void* const* d_in, const int* in_sizes, int n_in,
                              void* d_out, int out_size, void* d_ws, size_t ws_size,
                              hipStream_t stream) {
    const float* x  = (const float*)d_in[0];
    const float* Wk = (const float*)d_in[1];
    const float* Wq = (const float*)d_in[2];
    const float* Wv = (const float*)d_in[3];
    float* out = (float*)d_out;

    // Workspace layout (bytes): Wb 393216 | qs 2 MB | ks 2 MB | vT 2 MB  (~6.4 MB total)
    unsigned short* Wb = (unsigned short*)d_ws;
    unsigned short* qsb = (unsigned short*)((char*)d_ws + 393216);
    unsigned short* ksb = qsb + 1048576;
    unsigned short* vTb = ksb + 1048576;

    hipLaunchKernelGGL(wconv_kernel, dim3(768), dim3(256), 0, stream, Wk, Wq, Wv, Wb);
    hipLaunchKernelGGL(proj_kernel, dim3(256), dim3(256), 0, stream, x, Wb, qsb, ksb, vTb);
    hipLaunchKernelGGL(attn_kernel, dim3(128, 8), dim3(64), 0, stream, qsb, ksb, vTb, out);
}

// Round 2
// 215.469 us; speedup vs baseline: 1.3144x; 1.3144x over previous
//
#include <hip/hip_runtime.h>
#include <hip/hip_bf16.h>

typedef __attribute__((ext_vector_type(8))) short short8;
typedef __attribute__((ext_vector_type(4))) float float4v;

#define LOG2E 1.44269504088896340736f

__device__ __forceinline__ unsigned short f2bf(float f) {
    unsigned int u = __float_as_uint(f);
    unsigned int r = (u + 0x7fffu + ((u >> 16) & 1u)) >> 16;  // RNE
    return (unsigned short)r;
}

// ---------------------------------------------------------------------------
// Kernel 1: convert Wk|Wq|Wv (fp32) -> combined bf16 weight matrix Wb[192][1024]
// rows 0-63 = Wk, 64-127 = Wq, 128-191 = Wv
// ---------------------------------------------------------------------------
__global__ void wconv_kernel(const float* __restrict__ Wk, const float* __restrict__ Wq,
                             const float* __restrict__ Wv, unsigned short* __restrict__ Wb) {
    int i = blockIdx.x * 256 + threadIdx.x;  // 0..196607
    if (i >= 192 * 1024) return;
    float v;
    if (i < 65536)       v = Wk[i];
    else if (i < 131072) v = Wq[i - 65536];
    else                 v = Wv[i - 131072];
    Wb[i] = f2bf(v);
}

// ---------------------------------------------------------------------------
// Kernel 2: projection GEMM, N-split for occupancy.
// grid = (3, 256): blockIdx.x = output id (0=k,1=q,2=v) [fastest-varying so the
// 3 blocks sharing x rows are co-scheduled -> L2/L3 hits], blockIdx.y = row tile.
// Each wave: 16 rows x 64 cols, K=1024, with A-prefetch (1 wave/SIMD latency fix:
// now 3072 waves = 3/SIMD + software pipeline).
// ---------------------------------------------------------------------------
__global__ __launch_bounds__(256) void proj_kernel(
    const float* __restrict__ x, const unsigned short* __restrict__ Wb,
    unsigned short* __restrict__ qs, unsigned short* __restrict__ ks,
    unsigned short* __restrict__ vT) {
    const int lane = threadIdx.x & 63;
    const int wave = threadIdx.x >> 6;
    const int quad = lane >> 4;
    const int l16  = lane & 15;
    const int oid  = blockIdx.x;                       // 0=k, 1=q, 2=v
    const int rowA = blockIdx.y * 64 + wave * 16 + l16;

    const unsigned short* Wo = Wb + (size_t)oid * 64 * 1024;

    float4v acc[4];
#pragma unroll
    for (int n = 0; n < 4; n++) acc[n] = (float4v){0.f, 0.f, 0.f, 0.f};

    const float* xp = x + (size_t)rowA * 1024 + quad * 8;

    // prefetch iteration 0
    float4v a0 = *(const float4v*)(xp);
    float4v a1 = *(const float4v*)(xp + 4);

#pragma unroll 2
    for (int kc = 0; kc < 32; kc++) {
        short8 af;
#pragma unroll
        for (int j = 0; j < 4; j++) af[j] = (short)f2bf(a0[j]);
#pragma unroll
        for (int j = 0; j < 4; j++) af[4 + j] = (short)f2bf(a1[j]);
        // prefetch next A tile while MFMAs run on this one
        if (kc < 31) {
            a0 = *(const float4v*)(xp + (kc + 1) * 32);
            a1 = *(const float4v*)(xp + (kc + 1) * 32 + 4);
        }
#pragma unroll
        for (int n = 0; n < 4; n++) {
            const short8 bf = *(const short8*)(Wo + (size_t)(n * 16 + l16) * 1024 + kc * 32 + quad * 8);
            acc[n] = __builtin_amdgcn_mfma_f32_16x16x32_bf16(af, bf, acc[n], 0, 0, 0);
        }
    }

    // Epilogue. C layout: row = quad*4 + r, col = l16.
    const int rowD = blockIdx.y * 64 + wave * 16 + quad * 4;
#pragma unroll
    for (int r = 0; r < 4; r++) {
        const int t = rowD + r;
        const int b = t >> 11, tt = t & 2047;
        if (oid == 0) {
#pragma unroll
            for (int n = 0; n < 4; n++)
                ks[(size_t)t * 64 + n * 16 + l16] = f2bf(acc[n][r]);
        } else if (oid == 1) {
#pragma unroll
            for (int n = 0; n < 4; n++)  // fold in HS^-0.5 = 1/8 (exact in bf16)
                qs[(size_t)t * 64 + n * 16 + l16] = f2bf(acc[n][r] * 0.125f);
        } else {
#pragma unroll
            for (int n = 0; n < 4; n++)  // transposed store vT[b][o][t]
                vT[(size_t)b * 131072 + (size_t)(n * 16 + l16) * 2048 + tt] = f2bf(acc[n][r]);
        }
    }
}

// ---------------------------------------------------------------------------
// Kernel 3: causal flash attention, key-split across 4 waves (flash-decoding).
// grid = (128, 8), block = 256 (4 waves). All 4 waves share one 16-row Q tile;
// wave w processes key-blocks j == w (mod 4) with independent online softmax
// (partition-independent), then LDS rescale-merge. 4096 waves -> 16 waves/CU,
// all blocks co-resident; max serial depth 8 key-blocks (was 32).
// ---------------------------------------------------------------------------
__global__ __launch_bounds__(256) void attn_kernel(
    const unsigned short* __restrict__ qs, const unsigned short* __restrict__ ks,
    const unsigned short* __restrict__ vT, float* __restrict__ out) {
    __shared__ unsigned short P[4][16 * 72];  // per-wave C->A transpose, +8 pad (2-way alias = free)
    __shared__ float Ol[4][16 * 68];          // per-wave O, row stride 68 (pad for combine reads)
    __shared__ float Ml[4][16];
    __shared__ float Ll[4][16];

    const int lane = threadIdx.x & 63;
    const int wave = threadIdx.x >> 6;
    const int quad = lane >> 4;
    const int l16  = lane & 15;
    const int rt = blockIdx.x;   // 0..127
    const int b  = blockIdx.y;   // 0..7
    const int t0 = rt * 16;

    const unsigned short* qb = qs + (size_t)b * 131072;
    const unsigned short* kb = ks + (size_t)b * 131072;
    const unsigned short* vb = vT + (size_t)b * 131072;

    // Q fragments (A-operand): Q[t0+l16][kc*32 + quad*8 .. +7] — same for all waves (L2 hit)
    const short8 qf0 = *(const short8*)(qb + (size_t)(t0 + l16) * 64 + quad * 8);
    const short8 qf1 = *(const short8*)(qb + (size_t)(t0 + l16) * 64 + 32 + quad * 8);

    float4v o[4];
#pragma unroll
    for (int ot = 0; ot < 4; ot++) o[ot] = (float4v){0.f, 0.f, 0.f, 0.f};
    float mrow[4] = {-1e30f, -1e30f, -1e30f, -1e30f};
    float lrow[4] = {0.f, 0.f, 0.f, 0.f};

    const int nkb = t0 / 64 + 1;  // 64-key blocks needed (causal)
    for (int j = wave; j < nkb; j += 4) {
        const int key0 = j * 64;
        // ---- S = Q K^T over 64 keys (4 tiles of 16), HS=64 (2 MFMA steps) ----
        float4v s[4];
#pragma unroll
        for (int kt = 0; kt < 4; kt++) {
            const unsigned short* kr = kb + (size_t)(key0 + kt * 16 + l16) * 64 + quad * 8;
            const short8 kf0 = *(const short8*)(kr);
            const short8 kf1 = *(const short8*)(kr + 32);
            float4v z = (float4v){0.f, 0.f, 0.f, 0.f};
            z = __builtin_amdgcn_mfma_f32_16x16x32_bf16(qf0, kf0, z, 0, 0, 0);
            s[kt] = __builtin_amdgcn_mfma_f32_16x16x32_bf16(qf1, kf1, z, 0, 0, 0);
        }
        // ---- causal mask: only the diagonal block needs it ----
        if (j == nkb - 1) {
#pragma unroll
            for (int kt = 0; kt < 4; kt++) {
                const int key = key0 + kt * 16 + l16;
#pragma unroll
                for (int r = 0; r < 4; r++) {
                    if (key > t0 + quad * 4 + r) s[kt][r] = -1e30f;
                }
            }
        }
        // ---- online softmax (rows = quad*4 + r, replicated across 16 lanes) ----
        float mnew[4], alpha[4];
#pragma unroll
        for (int r = 0; r < 4; r++) {
            float mx = fmaxf(fmaxf(s[0][r], s[1][r]), fmaxf(s[2][r], s[3][r]));
            mx = fmaxf(mx, __shfl_xor(mx, 1));
            mx = fmaxf(mx, __shfl_xor(mx, 2));
            mx = fmaxf(mx, __shfl_xor(mx, 4));
            mx = fmaxf(mx, __shfl_xor(mx, 8));
            mnew[r]  = fmaxf(mrow[r], mx);
            alpha[r] = exp2f((mrow[r] - mnew[r]) * LOG2E);
            mrow[r]  = mnew[r];
        }
#pragma unroll
        for (int r = 0; r < 4; r++) {
            float rs = 0.f;
#pragma unroll
            for (int kt = 0; kt < 4; kt++) {
                float p = exp2f((s[kt][r] - mnew[r]) * LOG2E);
                rs += p;
                P[wave][(quad * 4 + r) * 72 + kt * 16 + l16] = f2bf(p);
            }
            rs += __shfl_xor(rs, 1);
            rs += __shfl_xor(rs, 2);
            rs += __shfl_xor(rs, 4);
            rs += __shfl_xor(rs, 8);
            lrow[r] = lrow[r] * alpha[r] + rs;
#pragma unroll
            for (int ot = 0; ot < 4; ot++) o[ot][r] *= alpha[r];
        }
        // ---- O += P @ V  (P via LDS C->A transpose; V from transposed vT) ----
#pragma unroll
        for (int kc = 0; kc < 2; kc++) {
            const short8 pf = *(const short8*)(&P[wave][l16 * 72 + kc * 32 + quad * 8]);
#pragma unroll
            for (int ot = 0; ot < 4; ot++) {
                const short8 vf = *(const short8*)(vb + (size_t)(ot * 16 + l16) * 2048 + key0 + kc * 32 + quad * 8);
                o[ot] = __builtin_amdgcn_mfma_f32_16x16x32_bf16(pf, vf, o[ot], 0, 0, 0);
            }
        }
    }

    // ---- publish per-wave partial state ----
#pragma unroll
    for (int r = 0; r < 4; r++) {
        if (l16 == 0) {
            Ml[wave][quad * 4 + r] = mrow[r];
            Ll[wave][quad * 4 + r] = lrow[r];
        }
#pragma unroll
        for (int ot = 0; ot < 4; ot++)
            Ol[wave][(quad * 4 + r) * 68 + ot * 16 + l16] = o[ot][r];
    }
    __syncthreads();

    // ---- block-wide merge: thread t -> row = t>>4, cols = (t&15)*4 .. +3 ----
    {
        const int row = threadIdx.x >> 4;
        const int c0  = (threadIdx.x & 15) * 4;
        float m0 = Ml[0][row], m1 = Ml[1][row], m2 = Ml[2][row], m3 = Ml[3][row];
        float mg = fmaxf(fmaxf(m0, m1), fmaxf(m2, m3));
        float s0 = exp2f((m0 - mg) * LOG2E);
        float s1 = exp2f((m1 - mg) * LOG2E);
        float s2 = exp2f((m2 - mg) * LOG2E);
        float s3 = exp2f((m3 - mg) * LOG2E);
        float lg = Ll[0][row] * s0 + Ll[1][row] * s1 + Ll[2][row] * s2 + Ll[3][row] * s3;
        float4v v0 = *(const float4v*)&Ol[0][row * 68 + c0];
        float4v v1 = *(const float4v*)&Ol[1][row * 68 + c0];
        float4v v2 = *(const float4v*)&Ol[2][row * 68 + c0];
        float4v v3 = *(const float4v*)&Ol[3][row * 68 + c0];
        float4v res;
        const float inv = 1.0f / lg;
#pragma unroll
        for (int j = 0; j < 4; j++)
            res[j] = (v0[j] * s0 + v1[j] * s1 + v2[j] * s2 + v3[j] * s3) * inv;
        float* ob = out + (size_t)b * 2048 * 64 + (size_t)(t0 + row) * 64 + c0;
        *(float4v*)ob = res;
    }
}

// ---------------------------------------------------------------------------
extern "C" void kernel_launch(void* const* d_in, const int* in_sizes, int n_in,
                              void* d_out, int out_size, void* d_ws, size_t ws_size,
                              hipStream_t stream) {
    const float* x  = (const float*)d_in[0];
    const float* Wk = (const float*)d_in[1];
    const float* Wq = (const float*)d_in[2];
    const float* Wv = (const float*)d_in[3];
    float* out = (float*)d_out;

    // Workspace layout (bytes): Wb 393216 | qs 2 MB | ks 2 MB | vT 2 MB  (~6.4 MB total)
    unsigned short* Wb = (unsigned short*)d_ws;
    unsigned short* qsb = (unsigned short*)((char*)d_ws + 393216);
    unsigned short* ksb = qsb + 1048576;
    unsigned short* vTb = ksb + 1048576;

    hipLaunchKernelGGL(wconv_kernel, dim3(768), dim3(256), 0, stream, Wk, Wq, Wv, Wb);
    hipLaunchKernelGGL(proj_kernel, dim3(3, 256), dim3(256), 0, stream, x, Wb, qsb, ksb, vTb);
    hipLaunchKernelGGL(attn_kernel, dim3(128, 8), dim3(256), 0, stream, qsb, ksb, vTb, out);
}

// Round 3
// 201.662 us; speedup vs baseline: 1.4044x; 1.0685x over previous
//
#include <hip/hip_runtime.h>
#include <hip/hip_bf16.h>

typedef __attribute__((ext_vector_type(8))) short short8;
typedef __attribute__((ext_vector_type(4))) float float4v;

#define LOG2E 1.44269504088896340736f

__device__ __forceinline__ unsigned short f2bf(float f) {
    unsigned int u = __float_as_uint(f);
    unsigned int r = (u + 0x7fffu + ((u >> 16) & 1u)) >> 16;  // RNE
    return (unsigned short)r;
}

// ---------------------------------------------------------------------------
// Kernel 1: convert Wk|Wq|Wv (fp32) -> combined bf16 weight matrix Wb[192][1024]
// rows 0-63 = Wk, 64-127 = Wq, 128-191 = Wv
// ---------------------------------------------------------------------------
__global__ void wconv_kernel(const float* __restrict__ Wk, const float* __restrict__ Wq,
                             const float* __restrict__ Wv, unsigned short* __restrict__ Wb) {
    int i = blockIdx.x * 256 + threadIdx.x;  // 0..196607
    if (i >= 192 * 1024) return;
    float v;
    if (i < 65536)       v = Wk[i];
    else if (i < 131072) v = Wq[i - 65536];
    else                 v = Wv[i - 131072];
    Wb[i] = f2bf(v);
}

// ---------------------------------------------------------------------------
// Kernel 2: projection GEMM, K-split for latency hiding.
// grid = 1024 blocks, one per 16-token row group. 4 waves per block; wave w
// owns K-slice [256w, 256w+256) and computes partial 16x192 in fp32; partials
// summed through LDS. x read ONCE (64 MB). A-loads: unconditional 4-deep
// prefetch, fully unrolled 8-iter loop -> deep outstanding-load queue
// (round-2 lesson: conditional prefetch defeated pipelining, 1875 cyc/iter).
// ---------------------------------------------------------------------------
__global__ __launch_bounds__(256, 4) void proj_kernel(
    const float* __restrict__ x, const unsigned short* __restrict__ Wb,
    unsigned short* __restrict__ qs, unsigned short* __restrict__ ks,
    unsigned short* __restrict__ vT) {
    __shared__ float R[4][6][256];  // 24 KB: cross-wave reduction, 2 phases of 6 tiles

    const int lane = threadIdx.x & 63;
    const int wave = threadIdx.x >> 6;
    const int quad = lane >> 4;
    const int l16  = lane & 15;
    const int t0   = blockIdx.x * 16;
    const int rowA = t0 + l16;

    float4v acc[12];
#pragma unroll
    for (int n = 0; n < 12; n++) acc[n] = (float4v){0.f, 0.f, 0.f, 0.f};

    const float* xp = x + (size_t)rowA * 1024 + wave * 256 + quad * 8;
    const unsigned short* Wp = Wb + wave * 256 + quad * 8;

    // prefetch first 4 K-chunks (8 loads in flight immediately)
    float4v abuf[4][2];
#pragma unroll
    for (int i = 0; i < 4; i++) {
        abuf[i][0] = *(const float4v*)(xp + i * 32);
        abuf[i][1] = *(const float4v*)(xp + i * 32 + 4);
    }

#pragma unroll
    for (int g = 0; g < 2; g++) {
#pragma unroll
        for (int i = 0; i < 4; i++) {
            short8 af;
#pragma unroll
            for (int j = 0; j < 4; j++) af[j] = (short)f2bf(abuf[i][0][j]);
#pragma unroll
            for (int j = 0; j < 4; j++) af[4 + j] = (short)f2bf(abuf[i][1][j]);
            if (g == 0) {  // compile-time after unroll: unconditional prefetch of chunk i+4
                abuf[i][0] = *(const float4v*)(xp + (4 + i) * 32);
                abuf[i][1] = *(const float4v*)(xp + (4 + i) * 32 + 4);
            }
            const int kc = g * 4 + i;
#pragma unroll
            for (int n = 0; n < 12; n++) {
                const short8 bf = *(const short8*)(Wp + (size_t)(n * 16 + l16) * 1024 + kc * 32);
                acc[n] = __builtin_amdgcn_mfma_f32_16x16x32_bf16(af, bf, acc[n], 0, 0, 0);
            }
        }
    }

    // ---- cross-wave K-reduction via LDS, phase A: tiles 0..5 (k-heads, q-heads 0..1)
#pragma unroll
    for (int n = 0; n < 6; n++)
#pragma unroll
        for (int r = 0; r < 4; r++)
            R[wave][n][(quad * 4 + r) * 16 + l16] = acc[n][r];
    __syncthreads();

    const int t   = threadIdx.x;
    const int row = t >> 4, col = t & 15;
    const int tg  = t0 + row;  // global token (block never crosses batch boundary)
#pragma unroll
    for (int n = 0; n < 6; n++) {
        const float s = R[0][n][t] + R[1][n][t] + R[2][n][t] + R[3][n][t];
        if (n < 4) ks[(size_t)tg * 64 + n * 16 + col] = f2bf(s);
        else       qs[(size_t)tg * 64 + (n - 4) * 16 + col] = f2bf(s * 0.125f);  // fold HS^-0.5
    }
    __syncthreads();

    // ---- phase B: tiles 6..11 (q-heads 2..3, v-heads 0..3)
#pragma unroll
    for (int n = 0; n < 6; n++)
#pragma unroll
        for (int r = 0; r < 4; r++)
            R[wave][n][(quad * 4 + r) * 16 + l16] = acc[6 + n][r];
    __syncthreads();

#pragma unroll
    for (int n = 0; n < 2; n++) {  // q heads 2,3
        const float s = R[0][n][t] + R[1][n][t] + R[2][n][t] + R[3][n][t];
        qs[(size_t)tg * 64 + (n + 2) * 16 + col] = f2bf(s * 0.125f);
    }
    {   // v heads: transposed thread mapping so vT stores are coalesced in tt
        const int rowV = t & 15, colV = t >> 4;
        const int idxV = rowV * 16 + colV;
        const int tgV  = t0 + rowV;
        const int bV   = tgV >> 11, ttV = tgV & 2047;
#pragma unroll
        for (int n = 2; n < 6; n++) {
            const float s = R[0][n][idxV] + R[1][n][idxV] + R[2][n][idxV] + R[3][n][idxV];
            vT[(size_t)bV * 131072 + (size_t)((n - 2) * 16 + colV) * 2048 + ttV] = f2bf(s);
        }
    }
}

// ---------------------------------------------------------------------------
// Kernel 3: causal flash attention, key-split across 4 waves (flash-decoding).
// grid = (128, 8), block = 256 (4 waves). All 4 waves share one 16-row Q tile;
// wave w processes key-blocks j == w (mod 4) with independent online softmax
// (partition-independent), then LDS rescale-merge. [unchanged from round 2]
// ---------------------------------------------------------------------------
__global__ __launch_bounds__(256) void attn_kernel(
    const unsigned short* __restrict__ qs, const unsigned short* __restrict__ ks,
    const unsigned short* __restrict__ vT, float* __restrict__ out) {
    __shared__ unsigned short P[4][16 * 72];  // per-wave C->A transpose, +8 pad (2-way alias = free)
    __shared__ float Ol[4][16 * 68];          // per-wave O, row stride 68 (pad for combine reads)
    __shared__ float Ml[4][16];
    __shared__ float Ll[4][16];

    const int lane = threadIdx.x & 63;
    const int wave = threadIdx.x >> 6;
    const int quad = lane >> 4;
    const int l16  = lane & 15;
    const int rt = blockIdx.x;   // 0..127
    const int b  = blockIdx.y;   // 0..7
    const int t0 = rt * 16;

    const unsigned short* qb = qs + (size_t)b * 131072;
    const unsigned short* kb = ks + (size_t)b * 131072;
    const unsigned short* vb = vT + (size_t)b * 131072;

    const short8 qf0 = *(const short8*)(qb + (size_t)(t0 + l16) * 64 + quad * 8);
    const short8 qf1 = *(const short8*)(qb + (size_t)(t0 + l16) * 64 + 32 + quad * 8);

    float4v o[4];
#pragma unroll
    for (int ot = 0; ot < 4; ot++) o[ot] = (float4v){0.f, 0.f, 0.f, 0.f};
    float mrow[4] = {-1e30f, -1e30f, -1e30f, -1e30f};
    float lrow[4] = {0.f, 0.f, 0.f, 0.f};

    const int nkb = t0 / 64 + 1;  // 64-key blocks needed (causal)
    for (int j = wave; j < nkb; j += 4) {
        const int key0 = j * 64;
        float4v s[4];
#pragma unroll
        for (int kt = 0; kt < 4; kt++) {
            const unsigned short* kr = kb + (size_t)(key0 + kt * 16 + l16) * 64 + quad * 8;
            const short8 kf0 = *(const short8*)(kr);
            const short8 kf1 = *(const short8*)(kr + 32);
            float4v z = (float4v){0.f, 0.f, 0.f, 0.f};
            z = __builtin_amdgcn_mfma_f32_16x16x32_bf16(qf0, kf0, z, 0, 0, 0);
            s[kt] = __builtin_amdgcn_mfma_f32_16x16x32_bf16(qf1, kf1, z, 0, 0, 0);
        }
        if (j == nkb - 1) {
#pragma unroll
            for (int kt = 0; kt < 4; kt++) {
                const int key = key0 + kt * 16 + l16;
#pragma unroll
                for (int r = 0; r < 4; r++) {
                    if (key > t0 + quad * 4 + r) s[kt][r] = -1e30f;
                }
            }
        }
        float mnew[4], alpha[4];
#pragma unroll
        for (int r = 0; r < 4; r++) {
            float mx = fmaxf(fmaxf(s[0][r], s[1][r]), fmaxf(s[2][r], s[3][r]));
            mx = fmaxf(mx, __shfl_xor(mx, 1));
            mx = fmaxf(mx, __shfl_xor(mx, 2));
            mx = fmaxf(mx, __shfl_xor(mx, 4));
            mx = fmaxf(mx, __shfl_xor(mx, 8));
            mnew[r]  = fmaxf(mrow[r], mx);
            alpha[r] = exp2f((mrow[r] - mnew[r]) * LOG2E);
            mrow[r]  = mnew[r];
        }
#pragma unroll
        for (int r = 0; r < 4; r++) {
            float rs = 0.f;
#pragma unroll
            for (int kt = 0; kt < 4; kt++) {
                float p = exp2f((s[kt][r] - mnew[r]) * LOG2E);
                rs += p;
                P[wave][(quad * 4 + r) * 72 + kt * 16 + l16] = f2bf(p);
            }
            rs += __shfl_xor(rs, 1);
            rs += __shfl_xor(rs, 2);
            rs += __shfl_xor(rs, 4);
            rs += __shfl_xor(rs, 8);
            lrow[r] = lrow[r] * alpha[r] + rs;
#pragma unroll
            for (int ot = 0; ot < 4; ot++) o[ot][r] *= alpha[r];
        }
#pragma unroll
        for (int kc = 0; kc < 2; kc++) {
            const short8 pf = *(const short8*)(&P[wave][l16 * 72 + kc * 32 + quad * 8]);
#pragma unroll
            for (int ot = 0; ot < 4; ot++) {
                const short8 vf = *(const short8*)(vb + (size_t)(ot * 16 + l16) * 2048 + key0 + kc * 32 + quad * 8);
                o[ot] = __builtin_amdgcn_mfma_f32_16x16x32_bf16(pf, vf, o[ot], 0, 0, 0);
            }
        }
    }

#pragma unroll
    for (int r = 0; r < 4; r++) {
        if (l16 == 0) {
            Ml[wave][quad * 4 + r] = mrow[r];
            Ll[wave][quad * 4 + r] = lrow[r];
        }
#pragma unroll
        for (int ot = 0; ot < 4; ot++)
            Ol[wave][(quad * 4 + r) * 68 + ot * 16 + l16] = o[ot][r];
    }
    __syncthreads();

    {
        const int row = threadIdx.x >> 4;
        const int c0  = (threadIdx.x & 15) * 4;
        float m0 = Ml[0][row], m1 = Ml[1][row], m2 = Ml[2][row], m3 = Ml[3][row];
        float mg = fmaxf(fmaxf(m0, m1), fmaxf(m2, m3));
        float s0 = exp2f((m0 - mg) * LOG2E);
        float s1 = exp2f((m1 - mg) * LOG2E);
        float s2 = exp2f((m2 - mg) * LOG2E);
        float s3 = exp2f((m3 - mg) * LOG2E);
        float lg = Ll[0][row] * s0 + Ll[1][row] * s1 + Ll[2][row] * s2 + Ll[3][row] * s3;
        float4v v0 = *(const float4v*)&Ol[0][row * 68 + c0];
        float4v v1 = *(const float4v*)&Ol[1][row * 68 + c0];
        float4v v2 = *(const float4v*)&Ol[2][row * 68 + c0];
        float4v v3 = *(const float4v*)&Ol[3][row * 68 + c0];
        float4v res;
        const float inv = 1.0f / lg;
#pragma unroll
        for (int j = 0; j < 4; j++)
            res[j] = (v0[j] * s0 + v1[j] * s1 + v2[j] * s2 + v3[j] * s3) * inv;
        float* ob = out + (size_t)b * 2048 * 64 + (size_t)(t0 + row) * 64 + c0;
        *(float4v*)ob = res;
    }
}

// ---------------------------------------------------------------------------
extern "C" void kernel_launch(void* const* d_in, const int* in_sizes, int n_in,
                              void* d_out, int out_size, void* d_ws, size_t ws_size,
                              hipStream_t stream) {
    const float* x  = (const float*)d_in[0];
    const float* Wk = (const float*)d_in[1];
    const float* Wq = (const float*)d_in[2];
    const float* Wv = (const float*)d_in[3];
    float* out = (float*)d_out;

    // Workspace layout (bytes): Wb 393216 | qs 2 MB | ks 2 MB | vT 2 MB  (~6.4 MB total)
    unsigned short* Wb = (unsigned short*)d_ws;
    unsigned short* qsb = (unsigned short*)((char*)d_ws + 393216);
    unsigned short* ksb = qsb + 1048576;
    unsigned short* vTb = ksb + 1048576;

    hipLaunchKernelGGL(wconv_kernel, dim3(768), dim3(256), 0, stream, Wk, Wq, Wv, Wb);
    hipLaunchKernelGGL(proj_kernel, dim3(1024), dim3(256), 0, stream, x, Wb, qsb, ksb, vTb);
    hipLaunchKernelGGL(attn_kernel, dim3(128, 8), dim3(256), 0, stream, qsb, ksb, vTb, out);
}

// Round 4
// 170.893 us; speedup vs baseline: 1.6573x; 1.1800x over previous
//
#include <hip/hip_runtime.h>
#include <hip/hip_bf16.h>

typedef __attribute__((ext_vector_type(8))) short short8;
typedef __attribute__((ext_vector_type(4))) float float4v;

#define LOG2E 1.44269504088896340736f

__device__ __forceinline__ unsigned short f2bf(float f) {
    unsigned int u = __float_as_uint(f);
    unsigned int r = (u + 0x7fffu + ((u >> 16) & 1u)) >> 16;  // RNE
    return (unsigned short)r;
}

// ---------------------------------------------------------------------------
// Kernel 1: convert Wk|Wq|Wv (fp32) -> combined bf16 weight matrix Wb[192][1024]
// ---------------------------------------------------------------------------
__global__ void wconv_kernel(const float* __restrict__ Wk, const float* __restrict__ Wq,
                             const float* __restrict__ Wv, unsigned short* __restrict__ Wb) {
    int i = blockIdx.x * 256 + threadIdx.x;
    if (i >= 192 * 1024) return;
    float v;
    if (i < 65536)       v = Wk[i];
    else if (i < 131072) v = Wq[i - 65536];
    else                 v = Wv[i - 131072];
    Wb[i] = f2bf(v);
}

// ---------------------------------------------------------------------------
// Kernel 2: projection GEMM with LDS-staged B (round-3 lesson: per-wave global
// B-loads serialize on L2 latency with no registers to pipeline them).
// grid = 256 blocks (64-row M-tile), 4 waves x (16 rows x 192 cols).
// B tile 192x64 double-buffered in LDS, row stride 72 (+8 pad: unpadded
// stride-64 puts all 16 l16-lanes on one bank group = 16-way conflict).
// Loads for iter kt+1 issued BEFORE compute of kt -> fly during MFMA phase;
// single barrier per iter. A rows are wave-private -> kept in registers with
// 1-iter prefetch, converted to bf16 at use.
// ---------------------------------------------------------------------------
__global__ __launch_bounds__(256) void proj_kernel(
    const float* __restrict__ x, const unsigned short* __restrict__ Wb,
    unsigned short* __restrict__ qs, unsigned short* __restrict__ ks,
    unsigned short* __restrict__ vT) {
    __shared__ unsigned short Bl[2][192 * 72];  // 54 KB total

    const int lane = threadIdx.x & 63;
    const int wave = threadIdx.x >> 6;
    const int quad = lane >> 4;
    const int l16  = lane & 15;
    const int t0   = blockIdx.x * 64;

    // B staging map: thread covers rows i*32 + wave*8 + lane/8, cols 8*(lane%8)
    const int srow8 = wave * 8 + (lane >> 3);
    const int scol  = (lane & 7) * 8;

    const int rowA = t0 + wave * 16 + l16;
    const float* xr = x + (size_t)rowA * 1024;

    float4v acc[12];
#pragma unroll
    for (int n = 0; n < 12; n++) acc[n] = (float4v){0.f, 0.f, 0.f, 0.f};

    // ---- preload k-chunk 0 ----
    short8 breg[6];
#pragma unroll
    for (int i = 0; i < 6; i++)
        breg[i] = *(const short8*)(Wb + (size_t)(i * 32 + srow8) * 1024 + scol);
    float4v areg[4];
    areg[0] = *(const float4v*)(xr + quad * 8);
    areg[1] = *(const float4v*)(xr + quad * 8 + 4);
    areg[2] = *(const float4v*)(xr + 32 + quad * 8);
    areg[3] = *(const float4v*)(xr + 32 + quad * 8 + 4);
#pragma unroll
    for (int i = 0; i < 6; i++)
        *(short8*)&Bl[0][(i * 32 + srow8) * 72 + scol] = breg[i];
    __syncthreads();

#pragma unroll 2
    for (int kt = 0; kt < 16; kt++) {
        const int kn = ((kt + 1) & 15) * 64;  // wraps at end: redundant, harmless
        // issue next-iteration loads (in flight during compute below)
        short8 bnext[6];
#pragma unroll
        for (int i = 0; i < 6; i++)
            bnext[i] = *(const short8*)(Wb + (size_t)(i * 32 + srow8) * 1024 + kn + scol);
        float4v anext[4];
        anext[0] = *(const float4v*)(xr + kn + quad * 8);
        anext[1] = *(const float4v*)(xr + kn + quad * 8 + 4);
        anext[2] = *(const float4v*)(xr + kn + 32 + quad * 8);
        anext[3] = *(const float4v*)(xr + kn + 32 + quad * 8 + 4);
        // compute on current buffer
        const unsigned short* Bc = Bl[kt & 1];
#pragma unroll
        for (int kc = 0; kc < 2; kc++) {
            short8 af;
#pragma unroll
            for (int j = 0; j < 4; j++) af[j] = (short)f2bf(areg[kc * 2][j]);
#pragma unroll
            for (int j = 0; j < 4; j++) af[4 + j] = (short)f2bf(areg[kc * 2 + 1][j]);
#pragma unroll
            for (int n = 0; n < 12; n++) {
                const short8 bf = *(const short8*)&Bc[(n * 16 + l16) * 72 + kc * 32 + quad * 8];
                acc[n] = __builtin_amdgcn_mfma_f32_16x16x32_bf16(af, bf, acc[n], 0, 0, 0);
            }
        }
        // stage next buffer (other buffer: last read was barrier-separated)
        unsigned short* Bn = (unsigned short*)Bl[(kt + 1) & 1];
#pragma unroll
        for (int i = 0; i < 6; i++)
            *(short8*)&Bn[(i * 32 + srow8) * 72 + scol] = bnext[i];
        __syncthreads();
#pragma unroll
        for (int i = 0; i < 4; i++) areg[i] = anext[i];
    }

    // Epilogue. C layout: row = quad*4 + r, col = l16.
    const int rowD = t0 + wave * 16 + quad * 4;
#pragma unroll
    for (int r = 0; r < 4; r++) {
        const int t = rowD + r;
        const int b = t >> 11, tt = t & 2047;
#pragma unroll
        for (int n = 0; n < 4; n++)
            ks[(size_t)t * 64 + n * 16 + l16] = f2bf(acc[n][r]);
#pragma unroll
        for (int n = 0; n < 4; n++)  // fold HS^-0.5 = 1/8 (exact in bf16)
            qs[(size_t)t * 64 + n * 16 + l16] = f2bf(acc[4 + n][r] * 0.125f);
#pragma unroll
        for (int n = 0; n < 4; n++)  // transposed store vT[b][o][t]
            vT[(size_t)b * 131072 + (size_t)(n * 16 + l16) * 2048 + tt] = f2bf(acc[8 + n][r]);
    }
}

// ---------------------------------------------------------------------------
// Kernel 3: causal flash attention, key-split across 4 waves.
// Round-4 changes: S computed TRANSPOSED (S^T = K Q^T, operand swap — A/B
// fragment layouts are identical) so each lane owns one Q-row's softmax:
// row reduce = 15 in-lane ops + 2 shuffles (was 4-deep shuffle chain x8);
// V loaded at iter top (independent of softmax); K prefetched next-iter;
// P written as packed ds_write_b64.
// ---------------------------------------------------------------------------
__global__ __launch_bounds__(256) void attn_kernel(
    const unsigned short* __restrict__ qs, const unsigned short* __restrict__ ks,
    const unsigned short* __restrict__ vT, float* __restrict__ out) {
    __shared__ unsigned short P[4][16 * 72];
    __shared__ float Ol[4][16 * 68];
    __shared__ float Ml[4][16];
    __shared__ float Ll[4][16];

    const int lane = threadIdx.x & 63;
    const int wave = threadIdx.x >> 6;
    const int quad = lane >> 4;
    const int l16  = lane & 15;
    const int rt = blockIdx.x;
    const int b  = blockIdx.y;
    const int t0 = rt * 16;

    const unsigned short* qb = qs + (size_t)b * 131072;
    const unsigned short* kb = ks + (size_t)b * 131072;
    const unsigned short* vb = vT + (size_t)b * 131072;

    const short8 qf0 = *(const short8*)(qb + (size_t)(t0 + l16) * 64 + quad * 8);
    const short8 qf1 = *(const short8*)(qb + (size_t)(t0 + l16) * 64 + 32 + quad * 8);

    float4v o[4];
#pragma unroll
    for (int ot = 0; ot < 4; ot++) o[ot] = (float4v){0.f, 0.f, 0.f, 0.f};
    float mrow = -1e30f, lrow = 0.f;

    const int nkb = t0 / 64 + 1;

    // preload K for first owned key-block (reads are in-bounds even if unused)
    short8 k0c[4], k1c[4];
#pragma unroll
    for (int kt = 0; kt < 4; kt++) {
        const unsigned short* kr = kb + (size_t)(wave * 64 + kt * 16 + l16) * 64 + quad * 8;
        k0c[kt] = *(const short8*)(kr);
        k1c[kt] = *(const short8*)(kr + 32);
    }

    for (int j = wave; j < nkb; j += 4) {
        const int key0 = j * 64;
        // V loads: independent of everything -> issue at top
        short8 vf[2][4];
#pragma unroll
        for (int kc = 0; kc < 2; kc++)
#pragma unroll
            for (int ot = 0; ot < 4; ot++)
                vf[kc][ot] = *(const short8*)(vb + (size_t)(ot * 16 + l16) * 2048 + key0 + kc * 32 + quad * 8);
        // K prefetch for next owned iteration
        const int jn = (j + 4 < nkb) ? j + 4 : j;
        short8 k0n[4], k1n[4];
#pragma unroll
        for (int kt = 0; kt < 4; kt++) {
            const unsigned short* kr = kb + (size_t)(jn * 64 + kt * 16 + l16) * 64 + quad * 8;
            k0n[kt] = *(const short8*)(kr);
            k1n[kt] = *(const short8*)(kr + 32);
        }
        // S^T = K Q^T: col = l16 = qrow, row = quad*4+r = key-in-tile
        float4v s[4];
#pragma unroll
        for (int kt = 0; kt < 4; kt++) {
            float4v z = (float4v){0.f, 0.f, 0.f, 0.f};
            z = __builtin_amdgcn_mfma_f32_16x16x32_bf16(k0c[kt], qf0, z, 0, 0, 0);
            s[kt] = __builtin_amdgcn_mfma_f32_16x16x32_bf16(k1c[kt], qf1, z, 0, 0, 0);
        }
        // causal mask on the diagonal block
        if (j == nkb - 1) {
            const int qrow = t0 + l16;
#pragma unroll
            for (int kt = 0; kt < 4; kt++)
#pragma unroll
                for (int r = 0; r < 4; r++)
                    if (key0 + kt * 16 + quad * 4 + r > qrow) s[kt][r] = -1e30f;
        }
        // online softmax: each lane owns qrow = l16 (replicated across quads)
        float mx = s[0][0];
#pragma unroll
        for (int kt = 0; kt < 4; kt++)
#pragma unroll
            for (int r = 0; r < 4; r++) mx = fmaxf(mx, s[kt][r]);
        mx = fmaxf(mx, __shfl_xor(mx, 16));
        mx = fmaxf(mx, __shfl_xor(mx, 32));
        const float mnew = fmaxf(mrow, mx);
        const float alpha = exp2f((mrow - mnew) * LOG2E);
        mrow = mnew;
        float rs = 0.f;
#pragma unroll
        for (int kt = 0; kt < 4; kt++) {
            float p0 = exp2f((s[kt][0] - mnew) * LOG2E);
            float p1 = exp2f((s[kt][1] - mnew) * LOG2E);
            float p2 = exp2f((s[kt][2] - mnew) * LOG2E);
            float p3 = exp2f((s[kt][3] - mnew) * LOG2E);
            rs += (p0 + p1) + (p2 + p3);
            unsigned int lo = (unsigned int)f2bf(p0) | ((unsigned int)f2bf(p1) << 16);
            unsigned int hi = (unsigned int)f2bf(p2) | ((unsigned int)f2bf(p3) << 16);
            unsigned long long w = ((unsigned long long)hi << 32) | lo;
            *(unsigned long long*)&P[wave][l16 * 72 + kt * 16 + quad * 4] = w;
        }
        rs += __shfl_xor(rs, 16);
        rs += __shfl_xor(rs, 32);
        lrow = lrow * alpha + rs;
        // rescale O (rows = quad*4+r; fetch that row's alpha from lane quad*4+r)
#pragma unroll
        for (int r = 0; r < 4; r++) {
            const float ar = __shfl(alpha, quad * 4 + r);
#pragma unroll
            for (int ot = 0; ot < 4; ot++) o[ot][r] *= ar;
        }
        // O += P V  (P: C->A transform via per-wave LDS tile)
#pragma unroll
        for (int kc = 0; kc < 2; kc++) {
            const short8 pf = *(const short8*)&P[wave][l16 * 72 + kc * 32 + quad * 8];
#pragma unroll
            for (int ot = 0; ot < 4; ot++)
                o[ot] = __builtin_amdgcn_mfma_f32_16x16x32_bf16(pf, vf[kc][ot], o[ot], 0, 0, 0);
        }
        // rotate prefetched K
#pragma unroll
        for (int kt = 0; kt < 4; kt++) { k0c[kt] = k0n[kt]; k1c[kt] = k1n[kt]; }
    }

    // publish per-wave partial state (mrow/lrow replicated over quads -> lanes 0-15)
    if (lane < 16) { Ml[wave][lane] = mrow; Ll[wave][lane] = lrow; }
#pragma unroll
    for (int r = 0; r < 4; r++)
#pragma unroll
        for (int ot = 0; ot < 4; ot++)
            Ol[wave][(quad * 4 + r) * 68 + ot * 16 + l16] = o[ot][r];
    __syncthreads();

    // block-wide merge: thread t -> row = t>>4, cols = (t&15)*4 .. +3
    {
        const int row = threadIdx.x >> 4;
        const int c0  = (threadIdx.x & 15) * 4;
        float m0 = Ml[0][row], m1 = Ml[1][row], m2 = Ml[2][row], m3 = Ml[3][row];
        float mg = fmaxf(fmaxf(m0, m1), fmaxf(m2, m3));
        float s0 = exp2f((m0 - mg) * LOG2E);
        float s1 = exp2f((m1 - mg) * LOG2E);
        float s2 = exp2f((m2 - mg) * LOG2E);
        float s3 = exp2f((m3 - mg) * LOG2E);
        float lg = Ll[0][row] * s0 + Ll[1][row] * s1 + Ll[2][row] * s2 + Ll[3][row] * s3;
        float4v v0 = *(const float4v*)&Ol[0][row * 68 + c0];
        float4v v1 = *(const float4v*)&Ol[1][row * 68 + c0];
        float4v v2 = *(const float4v*)&Ol[2][row * 68 + c0];
        float4v v3 = *(const float4v*)&Ol[3][row * 68 + c0];
        float4v res;
        const float inv = 1.0f / lg;
#pragma unroll
        for (int j = 0; j < 4; j++)
            res[j] = (v0[j] * s0 + v1[j] * s1 + v2[j] * s2 + v3[j] * s3) * inv;
        float* ob = out + (size_t)b * 2048 * 64 + (size_t)(t0 + row) * 64 + c0;
        *(float4v*)ob = res;
    }
}

// ---------------------------------------------------------------------------
extern "C" void kernel_launch(void* const* d_in, const int* in_sizes, int n_in,
                              void* d_out, int out_size, void* d_ws, size_t ws_size,
                              hipStream_t stream) {
    const float* x  = (const float*)d_in[0];
    const float* Wk = (const float*)d_in[1];
    const float* Wq = (const float*)d_in[2];
    const float* Wv = (const float*)d_in[3];
    float* out = (float*)d_out;

    unsigned short* Wb = (unsigned short*)d_ws;
    unsigned short* qsb = (unsigned short*)((char*)d_ws + 393216);
    unsigned short* ksb = qsb + 1048576;
    unsigned short* vTb = ksb + 1048576;

    hipLaunchKernelGGL(wconv_kernel, dim3(768), dim3(256), 0, stream, Wk, Wq, Wv, Wb);
    hipLaunchKernelGGL(proj_kernel, dim3(256), dim3(256), 0, stream, x, Wb, qsb, ksb, vTb);
    hipLaunchKernelGGL(attn_kernel, dim3(128, 8), dim3(256), 0, stream, qsb, ksb, vTb, out);
}

// Round 5
// 169.681 us; speedup vs baseline: 1.6691x; 1.0071x over previous
//
#include <hip/hip_runtime.h>
#include <hip/hip_bf16.h>

typedef __attribute__((ext_vector_type(8))) short short8;
typedef __attribute__((ext_vector_type(4))) float float4v;

#define LOG2E 1.44269504088896340736f

__device__ __forceinline__ unsigned short f2bf(float f) {
    unsigned int u = __float_as_uint(f);
    unsigned int r = (u + 0x7fffu + ((u >> 16) & 1u)) >> 16;  // RNE
    return (unsigned short)r;
}

// ---------------------------------------------------------------------------
// Kernel 1: convert Wk|Wq|Wv (fp32) -> combined bf16 weight matrix Wb[192][1024]
// ---------------------------------------------------------------------------
__global__ void wconv_kernel(const float* __restrict__ Wk, const float* __restrict__ Wq,
                             const float* __restrict__ Wv, unsigned short* __restrict__ Wb) {
    int i = blockIdx.x * 256 + threadIdx.x;
    if (i >= 192 * 1024) return;
    float v;
    if (i < 65536)       v = Wk[i];
    else if (i < 131072) v = Wq[i - 65536];
    else                 v = Wv[i - 131072];
    Wb[i] = f2bf(v);
}

// ---------------------------------------------------------------------------
// Kernel 2: projection GEMM. Round-5: 32-row M-tiles, grid 512 -> 2 blocks/CU,
// 8 waves/CU (was 4: barrier-lockstep with nothing to co-schedule). 4 waves:
// wave (w&1) = row group (16 rows), (w>>1) = n-tile group (6 of 12 tiles) ->
// per-wave LDS reads halved. B tile 192x64 double-buffered, +8 pad.
// ---------------------------------------------------------------------------
__global__ __launch_bounds__(256) void proj_kernel(
    const float* __restrict__ x, const unsigned short* __restrict__ Wb,
    unsigned short* __restrict__ qs, unsigned short* __restrict__ ks,
    unsigned short* __restrict__ vT) {
    __shared__ unsigned short Bl[2][192 * 72];  // 54 KB

    const int tid  = threadIdx.x;
    const int lane = tid & 63;
    const int wave = tid >> 6;
    const int rg   = wave & 1;   // row group
    const int g    = wave >> 1;  // n-tile group: 0 -> tiles 0..5, 1 -> tiles 6..11
    const int quad = lane >> 4;
    const int l16  = lane & 15;
    const int t0   = blockIdx.x * 32;

    // B staging: 256 threads x 6 short8: row = i*32 + tid/8, col = (tid&7)*8
    const int srow = tid >> 3;
    const int scol = (tid & 7) * 8;

    const int rowA = t0 + rg * 16 + l16;
    const float* xr = x + (size_t)rowA * 1024;

    float4v acc[6];
#pragma unroll
    for (int n = 0; n < 6; n++) acc[n] = (float4v){0.f, 0.f, 0.f, 0.f};

    // preload kc-block 0
    short8 breg[6];
#pragma unroll
    for (int i = 0; i < 6; i++)
        breg[i] = *(const short8*)(Wb + (size_t)(i * 32 + srow) * 1024 + scol);
    float4v areg[4];
    areg[0] = *(const float4v*)(xr + quad * 8);
    areg[1] = *(const float4v*)(xr + quad * 8 + 4);
    areg[2] = *(const float4v*)(xr + 32 + quad * 8);
    areg[3] = *(const float4v*)(xr + 32 + quad * 8 + 4);
#pragma unroll
    for (int i = 0; i < 6; i++)
        *(short8*)&Bl[0][(i * 32 + srow) * 72 + scol] = breg[i];
    __syncthreads();

#pragma unroll 2
    for (int kt = 0; kt < 16; kt++) {
        const int kn = ((kt + 1) & 15) * 64;  // wraps at end: redundant, harmless
        short8 bnext[6];
#pragma unroll
        for (int i = 0; i < 6; i++)
            bnext[i] = *(const short8*)(Wb + (size_t)(i * 32 + srow) * 1024 + kn + scol);
        float4v anext[4];
        anext[0] = *(const float4v*)(xr + kn + quad * 8);
        anext[1] = *(const float4v*)(xr + kn + quad * 8 + 4);
        anext[2] = *(const float4v*)(xr + kn + 32 + quad * 8);
        anext[3] = *(const float4v*)(xr + kn + 32 + quad * 8 + 4);
        const unsigned short* Bc = Bl[kt & 1];
#pragma unroll
        for (int kc = 0; kc < 2; kc++) {
            short8 af;
#pragma unroll
            for (int j = 0; j < 4; j++) af[j] = (short)f2bf(areg[kc * 2][j]);
#pragma unroll
            for (int j = 0; j < 4; j++) af[4 + j] = (short)f2bf(areg[kc * 2 + 1][j]);
#pragma unroll
            for (int n = 0; n < 6; n++) {
                const short8 bf = *(const short8*)&Bc[((g * 6 + n) * 16 + l16) * 72 + kc * 32 + quad * 8];
                acc[n] = __builtin_amdgcn_mfma_f32_16x16x32_bf16(af, bf, acc[n], 0, 0, 0);
            }
        }
        unsigned short* Bn = (unsigned short*)Bl[(kt + 1) & 1];
#pragma unroll
        for (int i = 0; i < 6; i++)
            *(short8*)&Bn[(i * 32 + srow) * 72 + scol] = bnext[i];
        __syncthreads();
#pragma unroll
        for (int i = 0; i < 4; i++) areg[i] = anext[i];
    }

    // Epilogue. C layout: row = quad*4 + r, col = l16.
    const int rowD = t0 + rg * 16 + quad * 4;
#pragma unroll
    for (int r = 0; r < 4; r++) {
        const int t = rowD + r;
        const int b = t >> 11, tt = t & 2047;
        if (g == 0) {
#pragma unroll
            for (int n = 0; n < 4; n++)
                ks[(size_t)t * 64 + n * 16 + l16] = f2bf(acc[n][r]);
#pragma unroll
            for (int n = 4; n < 6; n++)  // q tiles 0,1; fold HS^-0.5 = 1/8
                qs[(size_t)t * 64 + (n - 4) * 16 + l16] = f2bf(acc[n][r] * 0.125f);
        } else {
#pragma unroll
            for (int n = 0; n < 2; n++)  // q tiles 2,3
                qs[(size_t)t * 64 + (n + 2) * 16 + l16] = f2bf(acc[n][r] * 0.125f);
#pragma unroll
            for (int n = 2; n < 6; n++)  // v tiles, transposed store vT[b][o][t]
                vT[(size_t)b * 131072 + (size_t)((n - 2) * 16 + l16) * 2048 + tt] = f2bf(acc[n][r]);
        }
    }
}

// ---------------------------------------------------------------------------
// Kernel 3: causal flash attention, 4-way key-split, 128 KEYS PER ITERATION
// (round-5: halves iteration count -> halves fixed per-iter costs: max/sum
// shuffles, alpha, O-rescale bpermutes, LDS P round-trip, exposed load waits).
// K loaded in 2 register batches of 4 tiles (bounds VGPR); V batch issued
// before softmax so its latency hides under the exp2 chain.
// ---------------------------------------------------------------------------
__global__ __launch_bounds__(256) void attn_kernel(
    const unsigned short* __restrict__ qs, const unsigned short* __restrict__ ks,
    const unsigned short* __restrict__ vT, float* __restrict__ out) {
    __shared__ unsigned short P[4][16 * 136];  // 16 qrows x 128 keys, +8 pad
    __shared__ float Ol[4][16 * 68];
    __shared__ float Ml[4][16];
    __shared__ float Ll[4][16];

    const int lane = threadIdx.x & 63;
    const int wave = threadIdx.x >> 6;
    const int quad = lane >> 4;
    const int l16  = lane & 15;
    const int rt = blockIdx.x;
    const int b  = blockIdx.y;
    const int t0 = rt * 16;

    const unsigned short* qb = qs + (size_t)b * 131072;
    const unsigned short* kb = ks + (size_t)b * 131072;
    const unsigned short* vb = vT + (size_t)b * 131072;

    const short8 qf0 = *(const short8*)(qb + (size_t)(t0 + l16) * 64 + quad * 8);
    const short8 qf1 = *(const short8*)(qb + (size_t)(t0 + l16) * 64 + 32 + quad * 8);

    float4v o[4];
#pragma unroll
    for (int ot = 0; ot < 4; ot++) o[ot] = (float4v){0.f, 0.f, 0.f, 0.f};
    float mrow = -1e30f, lrow = 0.f;

    const int nkb2 = rt / 8 + 1;  // 128-key blocks needed (causal)

    for (int j = wave; j < nkb2; j += 4) {
        const int key0 = j * 128;
        // ---- S^T = K Q^T over 128 keys, two register batches of 4 key-tiles ----
        float4v s[8];
#pragma unroll
        for (int h = 0; h < 2; h++) {
            short8 k0[4], k1[4];
#pragma unroll
            for (int kt = 0; kt < 4; kt++) {
                const unsigned short* kr = kb + (size_t)(key0 + (h * 4 + kt) * 16 + l16) * 64 + quad * 8;
                k0[kt] = *(const short8*)(kr);
                k1[kt] = *(const short8*)(kr + 32);
            }
#pragma unroll
            for (int kt = 0; kt < 4; kt++) {
                float4v z = (float4v){0.f, 0.f, 0.f, 0.f};
                z = __builtin_amdgcn_mfma_f32_16x16x32_bf16(k0[kt], qf0, z, 0, 0, 0);
                s[h * 4 + kt] = __builtin_amdgcn_mfma_f32_16x16x32_bf16(k1[kt], qf1, z, 0, 0, 0);
            }
        }
        // ---- V loads: issue now, consumed after softmax (latency hidden) ----
        short8 vf[4][4];
#pragma unroll
        for (int kc = 0; kc < 4; kc++)
#pragma unroll
            for (int ot = 0; ot < 4; ot++)
                vf[kc][ot] = *(const short8*)(vb + (size_t)(ot * 16 + l16) * 2048 + key0 + kc * 32 + quad * 8);
        // ---- causal mask: only the diagonal 128-block ----
        if (j == nkb2 - 1) {
            const int qrow = t0 + l16;
#pragma unroll
            for (int kt = 0; kt < 8; kt++)
#pragma unroll
                for (int r = 0; r < 4; r++)
                    if (key0 + kt * 16 + quad * 4 + r > qrow) s[kt][r] = -1e30f;
        }
        // ---- online softmax: lane owns qrow = l16 (replicated across quads) ----
        float mx = s[0][0];
#pragma unroll
        for (int kt = 0; kt < 8; kt++)
#pragma unroll
            for (int r = 0; r < 4; r++) mx = fmaxf(mx, s[kt][r]);
        mx = fmaxf(mx, __shfl_xor(mx, 16));
        mx = fmaxf(mx, __shfl_xor(mx, 32));
        const float mnew = fmaxf(mrow, mx);
        const float alpha = exp2f((mrow - mnew) * LOG2E);
        mrow = mnew;
        float rs = 0.f;
#pragma unroll
        for (int kt = 0; kt < 8; kt++) {
            float p0 = exp2f((s[kt][0] - mnew) * LOG2E);
            float p1 = exp2f((s[kt][1] - mnew) * LOG2E);
            float p2 = exp2f((s[kt][2] - mnew) * LOG2E);
            float p3 = exp2f((s[kt][3] - mnew) * LOG2E);
            rs += (p0 + p1) + (p2 + p3);
            unsigned int lo = (unsigned int)f2bf(p0) | ((unsigned int)f2bf(p1) << 16);
            unsigned int hi = (unsigned int)f2bf(p2) | ((unsigned int)f2bf(p3) << 16);
            unsigned long long w = ((unsigned long long)hi << 32) | lo;
            *(unsigned long long*)&P[wave][l16 * 136 + kt * 16 + quad * 4] = w;
        }
        rs += __shfl_xor(rs, 16);
        rs += __shfl_xor(rs, 32);
        lrow = lrow * alpha + rs;
        // rescale O (rows = quad*4+r; that row's alpha lives in lane quad*4+r)
#pragma unroll
        for (int r = 0; r < 4; r++) {
            const float ar = __shfl(alpha, quad * 4 + r);
#pragma unroll
            for (int ot = 0; ot < 4; ot++) o[ot][r] *= ar;
        }
        // ---- O += P V ----
#pragma unroll
        for (int kc = 0; kc < 4; kc++) {
            const short8 pf = *(const short8*)&P[wave][l16 * 136 + kc * 32 + quad * 8];
#pragma unroll
            for (int ot = 0; ot < 4; ot++)
                o[ot] = __builtin_amdgcn_mfma_f32_16x16x32_bf16(pf, vf[kc][ot], o[ot], 0, 0, 0);
        }
    }

    // publish per-wave partial state (m/l replicated over quads -> lanes 0-15)
    if (lane < 16) { Ml[wave][lane] = mrow; Ll[wave][lane] = lrow; }
#pragma unroll
    for (int r = 0; r < 4; r++)
#pragma unroll
        for (int ot = 0; ot < 4; ot++)
            Ol[wave][(quad * 4 + r) * 68 + ot * 16 + l16] = o[ot][r];
    __syncthreads();

    // block-wide merge: thread t -> row = t>>4, cols = (t&15)*4 .. +3
    {
        const int row = threadIdx.x >> 4;
        const int c0  = (threadIdx.x & 15) * 4;
        float m0 = Ml[0][row], m1 = Ml[1][row], m2 = Ml[2][row], m3 = Ml[3][row];
        float mg = fmaxf(fmaxf(m0, m1), fmaxf(m2, m3));
        float s0 = exp2f((m0 - mg) * LOG2E);
        float s1 = exp2f((m1 - mg) * LOG2E);
        float s2 = exp2f((m2 - mg) * LOG2E);
        float s3 = exp2f((m3 - mg) * LOG2E);
        float lg = Ll[0][row] * s0 + Ll[1][row] * s1 + Ll[2][row] * s2 + Ll[3][row] * s3;
        float4v v0 = *(const float4v*)&Ol[0][row * 68 + c0];
        float4v v1 = *(const float4v*)&Ol[1][row * 68 + c0];
        float4v v2 = *(const float4v*)&Ol[2][row * 68 + c0];
        float4v v3 = *(const float4v*)&Ol[3][row * 68 + c0];
        float4v res;
        const float inv = 1.0f / lg;
#pragma unroll
        for (int j = 0; j < 4; j++)
            res[j] = (v0[j] * s0 + v1[j] * s1 + v2[j] * s2 + v3[j] * s3) * inv;
        float* ob = out + (size_t)b * 2048 * 64 + (size_t)(t0 + row) * 64 + c0;
        *(float4v*)ob = res;
    }
}

// ---------------------------------------------------------------------------
extern "C" void kernel_launch(void* const* d_in, const int* in_sizes, int n_in,
                              void* d_out, int out_size, void* d_ws, size_t ws_size,
                              hipStream_t stream) {
    const float* x  = (const float*)d_in[0];
    const float* Wk = (const float*)d_in[1];
    const float* Wq = (const float*)d_in[2];
    const float* Wv = (const float*)d_in[3];
    float* out = (float*)d_out;

    unsigned short* Wb = (unsigned short*)d_ws;
    unsigned short* qsb = (unsigned short*)((char*)d_ws + 393216);
    unsigned short* ksb = qsb + 1048576;
    unsigned short* vTb = ksb + 1048576;

    hipLaunchKernelGGL(wconv_kernel, dim3(768), dim3(256), 0, stream, Wk, Wq, Wv, Wb);
    hipLaunchKernelGGL(proj_kernel, dim3(512), dim3(256), 0, stream, x, Wb, qsb, ksb, vTb);
    hipLaunchKernelGGL(attn_kernel, dim3(128, 8), dim3(256), 0, stream, qsb, ksb, vTb, out);
}